// Round 1
// baseline (549.297 us; speedup 1.0000x reference)
//
#include <hip/hip_runtime.h>
#include <math.h>

#define D 128
#define TWO_D 256
#define B_SZ 1024
#define KNB 200

__device__ __forceinline__ float sigmoid_f(float x) { return 1.f / (1.f + __expf(-x)); }
__device__ __forceinline__ float tanh_fast(float x) { return 1.f - 2.f / (__expf(2.f * x) + 1.f); }

// ---------------------------------------------------------------------------
// Kernel 1: gather+sum, GCN linear, support encoder (FFN+residual+LayerNorm),
// and the query-row gather.  One block per batch row b.  256 threads.
// ---------------------------------------------------------------------------
__global__ __launch_bounds__(256) void k_support(
    const int* __restrict__ relations, const int* __restrict__ entities,
    const int* __restrict__ query, const float* __restrict__ emb,
    const float* __restrict__ gcn_w, const float* __restrict__ gcn_b,
    const float* __restrict__ p1_w, const float* __restrict__ p1_b,
    const float* __restrict__ p2_w, const float* __restrict__ p2_b,
    const float* __restrict__ ln_a, const float* __restrict__ ln_b,
    float* __restrict__ sg, float* __restrict__ qbuf)
{
    __shared__ int idxs[2 * KNB];
    __shared__ __align__(16) float S[TWO_D];
    __shared__ __align__(16) float sup[D];
    __shared__ __align__(16) float hid[TWO_D];
    __shared__ __align__(16) float zv[D];
    __shared__ float red2[2];

    const int b = blockIdx.x;
    const int t = threadIdx.x;

    for (int i = t; i < KNB; i += 256) idxs[i] = relations[b * KNB + i];
    for (int i = t; i < KNB; i += 256) idxs[KNB + i] = entities[b * KNB + i];
    __syncthreads();

    // gather-sum: S[0:128] = sum_k emb[rel], S[128:256] = sum_k emb[ent]
    float acc = 0.f;
    if (t < D) {
        const int d = t;
        #pragma unroll 8
        for (int k = 0; k < KNB; ++k) acc += emb[idxs[k] * D + d];
    } else {
        const int d = t - D;
        #pragma unroll 8
        for (int k = 0; k < KNB; ++k) acc += emb[idxs[KNB + k] * D + d];
    }
    S[t] = acc;
    __syncthreads();

    // support[d] = tanh((S . gcn_w[d,:] + 200*b[d]) / 1024)   (num_neighbors = B = 1024!)
    if (t < D) {
        const float4* w4 = (const float4*)(gcn_w + t * TWO_D);
        float dot = 0.f;
        #pragma unroll 8
        for (int f = 0; f < TWO_D / 4; ++f) {
            float4 w = w4[f];
            float4 s = *(const float4*)&S[f * 4];
            dot += w.x * s.x + w.y * s.y + w.z * s.z + w.w * s.w;
        }
        float v = (dot + 200.f * gcn_b[t]) * (1.f / 1024.f);
        sup[t] = tanhf(v);
    }
    __syncthreads();

    // hidden = relu(support @ p1_w.T + p1_b)    (all 256 threads)
    {
        const float4* w4 = (const float4*)(p1_w + t * D);
        float dot = 0.f;
        #pragma unroll 8
        for (int f = 0; f < D / 4; ++f) {
            float4 w = w4[f];
            float4 s = *(const float4*)&sup[f * 4];
            dot += w.x * s.x + w.y * s.y + w.z * s.z + w.w * s.w;
        }
        float h = dot + p1_b[t];
        hid[t] = h > 0.f ? h : 0.f;
    }
    __syncthreads();

    // z = hidden @ p2_w.T + p2_b + support
    if (t < D) {
        const float4* w4 = (const float4*)(p2_w + t * TWO_D);
        float dot = 0.f;
        #pragma unroll 8
        for (int f = 0; f < TWO_D / 4; ++f) {
            float4 w = w4[f];
            float4 s = *(const float4*)&hid[f * 4];
            dot += w.x * s.x + w.y * s.y + w.z * s.z + w.w * s.w;
        }
        zv[t] = dot + p2_b[t] + sup[t];
    }
    __syncthreads();

    // LayerNorm (unbiased std, eps added to std) via one wave
    if (t < 64) {
        float x0 = zv[t], x1 = zv[t + 64];
        float s = x0 + x1;
        for (int off = 32; off; off >>= 1) s += __shfl_down(s, off);
        float mu = __shfl(s, 0) * (1.f / 128.f);
        float d0 = x0 - mu, d1 = x1 - mu;
        float v = d0 * d0 + d1 * d1;
        for (int off = 32; off; off >>= 1) v += __shfl_down(v, off);
        v = __shfl(v, 0);
        if (t == 0) { red2[0] = mu; red2[1] = sqrtf(v * (1.f / 127.f)); }
    }
    __syncthreads();
    if (t < D) {
        float mu = red2[0], sigma = red2[1];
        sg[b * D + t] = (zv[t] - mu) / (sigma + 1e-3f) * ln_a[t] + ln_b[t];
        qbuf[b * D + t] = emb[query[b] * D + t];
    }
}

// ---------------------------------------------------------------------------
// Kernel 2: gates GEMM (1024 x [4 gates x 256] x K) + fused LSTM pointwise.
// x = [q | h_out_prev | r_prev] (three 128-wide planes), W = [w_ih | w_hh].
// Block tile: 32 b-rows x 32 n-cols x 4 gates. Grid (32, 8).
// ---------------------------------------------------------------------------
__global__ __launch_bounds__(256) void k_gates(
    const float* __restrict__ qb, const float* __restrict__ hb,
    const float* __restrict__ rb, const float* __restrict__ w_ih,
    const float* __restrict__ w_hh, const float* __restrict__ b_ih,
    const float* __restrict__ b_hh, float* __restrict__ cbuf,
    float* __restrict__ hout, int kend)
{
    __shared__ __align__(16) float As[32][36];
    __shared__ __align__(16) float Ws[4][32][33];

    const int b0 = blockIdx.x * 32;
    const int n0 = blockIdx.y * 32;
    const int t = threadIdx.x;
    const int tx = t & 31, ty = t >> 5;

    float acc[4][4] = {};

    for (int k0 = 0; k0 < kend; k0 += 32) {
        const int seg = k0 >> 7;  // 0: q, 1: h_out_prev, 2: r_prev
        const float* xsrc = (seg == 0) ? qb : ((seg == 1) ? hb : rb);
        const int c0 = k0 & 127;
        {
            const int kk = t & 31, i0 = t >> 5;
            #pragma unroll
            for (int i = i0; i < 32; i += 8)
                As[kk][i] = xsrc[(b0 + i) * D + c0 + kk];
        }
        {
            const int kk = t & 31, j0 = t >> 5;
            #pragma unroll
            for (int g = 0; g < 4; ++g) {
                const int grow = g * 256 + n0;
                #pragma unroll
                for (int j = j0; j < 32; j += 8) {
                    float w;
                    if (k0 < 128) w = w_ih[(grow + j) * D + k0 + kk];
                    else          w = w_hh[(grow + j) * TWO_D + (k0 - 128) + kk];
                    Ws[g][kk][j] = w;
                }
            }
        }
        __syncthreads();
        #pragma unroll
        for (int kc = 0; kc < 32; ++kc) {
            float4 av = *(const float4*)&As[kc][ty * 4];
            float w0 = Ws[0][kc][tx], w1 = Ws[1][kc][tx];
            float w2 = Ws[2][kc][tx], w3 = Ws[3][kc][tx];
            acc[0][0] += av.x * w0; acc[0][1] += av.x * w1; acc[0][2] += av.x * w2; acc[0][3] += av.x * w3;
            acc[1][0] += av.y * w0; acc[1][1] += av.y * w1; acc[1][2] += av.y * w2; acc[1][3] += av.y * w3;
            acc[2][0] += av.z * w0; acc[2][1] += av.z * w1; acc[2][2] += av.z * w2; acc[2][3] += av.z * w3;
            acc[3][0] += av.w * w0; acc[3][1] += av.w * w1; acc[3][2] += av.w * w2; acc[3][3] += av.w * w3;
        }
        __syncthreads();
    }

    const int n = n0 + tx;
    const float bi0 = b_ih[n] + b_hh[n];
    const float bi1 = b_ih[256 + n] + b_hh[256 + n];
    const float bi2 = b_ih[512 + n] + b_hh[512 + n];
    const float bi3 = b_ih[768 + n] + b_hh[768 + n];
    #pragma unroll
    for (int i = 0; i < 4; ++i) {
        const int b = b0 + ty * 4 + i;
        float gi = acc[i][0] + bi0;
        float gf = acc[i][1] + bi1;
        float gg = acc[i][2] + bi2;
        float go = acc[i][3] + bi3;
        float cold = cbuf[b * TWO_D + n];
        float cnew = sigmoid_f(gf) * cold + sigmoid_f(gi) * tanh_fast(gg);
        cbuf[b * TWO_D + n] = cnew;
        if (n < D) {
            float h = sigmoid_f(go) * tanh_fast(cnew);
            hout[b * D + n] = qb[b * D + n] + h;
        }
    }
}

// ---------------------------------------------------------------------------
// Kernel 3: scores = h_out @ sg^T  (1024x1024, K=128). 64x64 tiles, grid (16,16).
// ---------------------------------------------------------------------------
__global__ __launch_bounds__(256) void k_scores(
    const float* __restrict__ hout, const float* __restrict__ sg,
    float* __restrict__ scores)
{
    __shared__ __align__(16) float As[32][68];
    __shared__ __align__(16) float Bs[32][68];

    const int b0 = blockIdx.x * 64;
    const int j0 = blockIdx.y * 64;
    const int t = threadIdx.x;
    const int tx = t & 15, ty = t >> 4;

    float acc[4][4] = {};

    for (int k0 = 0; k0 < D; k0 += 32) {
        const int kk = t & 31, i0 = t >> 5;
        #pragma unroll
        for (int i = i0; i < 64; i += 8) {
            As[kk][i] = hout[(b0 + i) * D + k0 + kk];
            Bs[kk][i] = sg[(j0 + i) * D + k0 + kk];
        }
        __syncthreads();
        #pragma unroll
        for (int kc = 0; kc < 32; ++kc) {
            float4 av = *(const float4*)&As[kc][ty * 4];
            float4 bv = *(const float4*)&Bs[kc][tx * 4];
            acc[0][0] += av.x * bv.x; acc[0][1] += av.x * bv.y; acc[0][2] += av.x * bv.z; acc[0][3] += av.x * bv.w;
            acc[1][0] += av.y * bv.x; acc[1][1] += av.y * bv.y; acc[1][2] += av.y * bv.z; acc[1][3] += av.y * bv.w;
            acc[2][0] += av.z * bv.x; acc[2][1] += av.z * bv.y; acc[2][2] += av.z * bv.z; acc[2][3] += av.z * bv.w;
            acc[3][0] += av.w * bv.x; acc[3][1] += av.w * bv.y; acc[3][2] += av.w * bv.z; acc[3][3] += av.w * bv.w;
        }
        __syncthreads();
    }
    #pragma unroll
    for (int i = 0; i < 4; ++i) {
        float4 v = make_float4(acc[i][0], acc[i][1], acc[i][2], acc[i][3]);
        *(float4*)&scores[(b0 + ty * 4 + i) * B_SZ + j0 + tx * 4] = v;
    }
}

// ---------------------------------------------------------------------------
// Kernel 4: per-row softmax stats (max, 1/sumexp). One block per row.
// ---------------------------------------------------------------------------
__global__ __launch_bounds__(256) void k_stats(
    const float* __restrict__ scores, float2* __restrict__ stats)
{
    __shared__ float red[4];
    __shared__ float smx;
    const int b = blockIdx.x, t = threadIdx.x;
    const float* row = scores + b * B_SZ;
    float v0 = row[t], v1 = row[t + 256], v2 = row[t + 512], v3 = row[t + 768];
    float m = fmaxf(fmaxf(v0, v1), fmaxf(v2, v3));
    for (int off = 32; off; off >>= 1) m = fmaxf(m, __shfl_down(m, off));
    if ((t & 63) == 0) red[t >> 6] = m;
    __syncthreads();
    if (t == 0) smx = fmaxf(fmaxf(red[0], red[1]), fmaxf(red[2], red[3]));
    __syncthreads();
    const float mx = smx;
    float s = __expf(v0 - mx) + __expf(v1 - mx) + __expf(v2 - mx) + __expf(v3 - mx);
    for (int off = 32; off; off >>= 1) s += __shfl_down(s, off);
    __syncthreads();
    if ((t & 63) == 0) red[t >> 6] = s;
    __syncthreads();
    if (t == 0) stats[b] = make_float2(mx, 1.f / (red[0] + red[1] + red[2] + red[3]));
}

// ---------------------------------------------------------------------------
// Kernel 5: r = softmax(scores) @ sg  (1024x128, K=1024), softmax on the fly.
// Split-K x8 with f32 atomics. Grid (32, 4, 8), 32x32 tiles.
// ---------------------------------------------------------------------------
__global__ __launch_bounds__(256) void k_rgemm(
    const float* __restrict__ scores, const float2* __restrict__ stats,
    const float* __restrict__ sg, float* __restrict__ rbuf)
{
    __shared__ __align__(16) float As[32][36];
    __shared__ __align__(16) float Bs[32][33];
    __shared__ float mx[32], is[32];

    const int b0 = blockIdx.x * 32;
    const int n0 = blockIdx.y * 32;
    const int kbase = blockIdx.z * 128;
    const int t = threadIdx.x;
    const int tx = t & 31, ty = t >> 5;

    if (t < 32) { float2 st = stats[b0 + t]; mx[t] = st.x; is[t] = st.y; }
    __syncthreads();

    float acc[4] = {0.f, 0.f, 0.f, 0.f};

    for (int k0 = kbase; k0 < kbase + 128; k0 += 32) {
        {
            const int kk = t & 31, i0 = t >> 5;
            #pragma unroll
            for (int i = i0; i < 32; i += 8) {
                float v = scores[(b0 + i) * B_SZ + k0 + kk];
                As[kk][i] = __expf(v - mx[i]) * is[i];
            }
            const int cc = t & 31, kc0 = t >> 5;
            #pragma unroll
            for (int kc = kc0; kc < 32; kc += 8)
                Bs[kc][cc] = sg[(k0 + kc) * D + n0 + cc];
        }
        __syncthreads();
        #pragma unroll
        for (int kc = 0; kc < 32; ++kc) {
            float bv = Bs[kc][tx];
            float4 av = *(const float4*)&As[kc][ty * 4];
            acc[0] += av.x * bv;
            acc[1] += av.y * bv;
            acc[2] += av.z * bv;
            acc[3] += av.w * bv;
        }
        __syncthreads();
    }
    #pragma unroll
    for (int i = 0; i < 4; ++i)
        atomicAdd(&rbuf[(b0 + ty * 4 + i) * D + n0 + tx], acc[i]);
}

// ---------------------------------------------------------------------------
// Kernel 6: cosine similarity per row. One wave per row.
// ---------------------------------------------------------------------------
__global__ __launch_bounds__(64) void k_cosine(
    const float* __restrict__ hout, const float* __restrict__ sg,
    float* __restrict__ out)
{
    const int b = blockIdx.x, t = threadIdx.x;
    float a0 = hout[b * D + t], a1 = hout[b * D + t + 64];
    float s0 = sg[b * D + t], s1 = sg[b * D + t + 64];
    float cr = a0 * s0 + a1 * s1;
    float n1 = a0 * a0 + a1 * a1;
    float n2 = s0 * s0 + s1 * s1;
    for (int off = 32; off; off >>= 1) {
        cr += __shfl_down(cr, off);
        n1 += __shfl_down(n1, off);
        n2 += __shfl_down(n2, off);
    }
    if (t == 0) out[b] = cr / sqrtf(n1 * n2);
}

// ---------------------------------------------------------------------------
extern "C" void kernel_launch(void* const* d_in, const int* in_sizes, int n_in,
                              void* d_out, int out_size, void* d_ws, size_t ws_size,
                              hipStream_t stream)
{
    const int*   relations = (const int*)d_in[0];
    const int*   entities  = (const int*)d_in[1];
    const int*   query     = (const int*)d_in[2];
    const float* emb       = (const float*)d_in[3];
    const float* gcn_w     = (const float*)d_in[4];
    const float* gcn_b     = (const float*)d_in[5];
    const float* p1_w      = (const float*)d_in[6];
    const float* p1_b      = (const float*)d_in[7];
    const float* p2_w      = (const float*)d_in[8];
    const float* p2_b      = (const float*)d_in[9];
    const float* ln_a      = (const float*)d_in[10];
    const float* ln_b      = (const float*)d_in[11];
    const float* w_ih      = (const float*)d_in[12];
    const float* w_hh      = (const float*)d_in[13];
    const float* b_ih      = (const float*)d_in[14];
    const float* b_hh      = (const float*)d_in[15];

    float* ws = (float*)d_ws;
    float*  sg     = ws;                    // 1024*128
    float*  qb     = ws + 131072;           // 1024*128
    float*  hoA    = ws + 262144;           // 1024*128
    float*  hoB    = ws + 393216;           // 1024*128
    float*  rb     = ws + 524288;           // 1024*128
    float*  cb     = ws + 655360;           // 1024*256
    float*  scores = ws + 917504;           // 1024*1024
    float2* stats  = (float2*)(ws + 1966080); // 1024 float2

    // c carries across steps and must start at zero; h_out_prev / r_prev are
    // never read at step 0 (kend=128 skips their K-segments).
    hipMemsetAsync(cb, 0, 262144 * sizeof(float), stream);

    k_support<<<dim3(B_SZ), dim3(256), 0, stream>>>(
        relations, entities, query, emb, gcn_w, gcn_b,
        p1_w, p1_b, p2_w, p2_b, ln_a, ln_b, sg, qb);

    float* hin = hoA;
    float* hcur = hoB;
    for (int s = 0; s < 4; ++s) {
        const int kend = (s == 0) ? 128 : 384;  // step 0: h_r == 0
        k_gates<<<dim3(32, 8), dim3(256), 0, stream>>>(
            qb, hin, rb, w_ih, w_hh, b_ih, b_hh, cb, hcur, kend);
        if (s < 3) {  // step 3's attention output is dead
            k_scores<<<dim3(16, 16), dim3(256), 0, stream>>>(hcur, sg, scores);
            k_stats<<<dim3(B_SZ), dim3(256), 0, stream>>>(scores, stats);
            hipMemsetAsync(rb, 0, 131072 * sizeof(float), stream);
            k_rgemm<<<dim3(32, 4, 8), dim3(256), 0, stream>>>(scores, stats, sg, rb);
        }
        float* tmp = hin; hin = hcur; hcur = tmp;
    }
    k_cosine<<<dim3(B_SZ), dim3(64), 0, stream>>>(hin, sg, (float*)d_out);
}

// Round 2
// 407.712 us; speedup vs baseline: 1.3473x; 1.3473x over previous
//
#include <hip/hip_runtime.h>
#include <math.h>

#define D 128
#define TWO_D 256
#define B_SZ 1024
#define KNB 200
#define AW 392  // padded LDS stride (fp16) for gates A tile

typedef _Float16 half8 __attribute__((ext_vector_type(8)));
typedef _Float16 half4 __attribute__((ext_vector_type(4)));
typedef float floatx4 __attribute__((ext_vector_type(4)));

__device__ __forceinline__ float sigmoid_f(float x) { return 1.f / (1.f + __expf(-x)); }
__device__ __forceinline__ float tanh_fast(float x) { return 1.f - 2.f / (__expf(2.f * x) + 1.f); }

__device__ __forceinline__ half8 cvt8(const float* p) {
    float4 v0 = *(const float4*)p;
    float4 v1 = *(const float4*)(p + 4);
    half8 r;
    r[0] = (_Float16)v0.x; r[1] = (_Float16)v0.y; r[2] = (_Float16)v0.z; r[3] = (_Float16)v0.w;
    r[4] = (_Float16)v1.x; r[5] = (_Float16)v1.y; r[6] = (_Float16)v1.z; r[7] = (_Float16)v1.w;
    return r;
}

// ---------------------------------------------------------------------------
// Kernel 1: gather+sum, GCN linear, support encoder (FFN+residual+LayerNorm),
// query-row gather, and sg fp16-transpose for the r-GEMM. One block per row b.
// ---------------------------------------------------------------------------
__global__ __launch_bounds__(256) void k_support(
    const int* __restrict__ relations, const int* __restrict__ entities,
    const int* __restrict__ query, const float* __restrict__ emb,
    const float* __restrict__ gcn_w, const float* __restrict__ gcn_b,
    const float* __restrict__ p1_w, const float* __restrict__ p1_b,
    const float* __restrict__ p2_w, const float* __restrict__ p2_b,
    const float* __restrict__ ln_a, const float* __restrict__ ln_b,
    float* __restrict__ sg, _Float16* __restrict__ sgT, float* __restrict__ qbuf)
{
    __shared__ int idxs[2 * KNB];
    __shared__ __align__(16) float S[TWO_D];
    __shared__ __align__(16) float sup[D];
    __shared__ __align__(16) float hid[TWO_D];
    __shared__ __align__(16) float zv[D];
    __shared__ float red2[2];

    const int b = blockIdx.x;
    const int t = threadIdx.x;

    for (int i = t; i < KNB; i += 256) idxs[i] = relations[b * KNB + i];
    for (int i = t; i < KNB; i += 256) idxs[KNB + i] = entities[b * KNB + i];
    __syncthreads();

    float acc = 0.f;
    if (t < D) {
        const int d = t;
        #pragma unroll 8
        for (int k = 0; k < KNB; ++k) acc += emb[idxs[k] * D + d];
    } else {
        const int d = t - D;
        #pragma unroll 8
        for (int k = 0; k < KNB; ++k) acc += emb[idxs[KNB + k] * D + d];
    }
    S[t] = acc;
    __syncthreads();

    if (t < D) {
        const float4* w4 = (const float4*)(gcn_w + t * TWO_D);
        float dot = 0.f;
        #pragma unroll 8
        for (int f = 0; f < TWO_D / 4; ++f) {
            float4 w = w4[f];
            float4 s = *(const float4*)&S[f * 4];
            dot += w.x * s.x + w.y * s.y + w.z * s.z + w.w * s.w;
        }
        float v = (dot + 200.f * gcn_b[t]) * (1.f / 1024.f);  // num_neighbors = B = 1024
        sup[t] = tanhf(v);
    }
    __syncthreads();

    {
        const float4* w4 = (const float4*)(p1_w + t * D);
        float dot = 0.f;
        #pragma unroll 8
        for (int f = 0; f < D / 4; ++f) {
            float4 w = w4[f];
            float4 s = *(const float4*)&sup[f * 4];
            dot += w.x * s.x + w.y * s.y + w.z * s.z + w.w * s.w;
        }
        float h = dot + p1_b[t];
        hid[t] = h > 0.f ? h : 0.f;
    }
    __syncthreads();

    if (t < D) {
        const float4* w4 = (const float4*)(p2_w + t * TWO_D);
        float dot = 0.f;
        #pragma unroll 8
        for (int f = 0; f < TWO_D / 4; ++f) {
            float4 w = w4[f];
            float4 s = *(const float4*)&hid[f * 4];
            dot += w.x * s.x + w.y * s.y + w.z * s.z + w.w * s.w;
        }
        zv[t] = dot + p2_b[t] + sup[t];
    }
    __syncthreads();

    if (t < 64) {
        float x0 = zv[t], x1 = zv[t + 64];
        float s = x0 + x1;
        for (int off = 32; off; off >>= 1) s += __shfl_down(s, off);
        float mu = __shfl(s, 0) * (1.f / 128.f);
        float d0 = x0 - mu, d1 = x1 - mu;
        float v = d0 * d0 + d1 * d1;
        for (int off = 32; off; off >>= 1) v += __shfl_down(v, off);
        v = __shfl(v, 0);
        if (t == 0) { red2[0] = mu; red2[1] = sqrtf(v * (1.f / 127.f)); }
    }
    __syncthreads();
    if (t < D) {
        float mu = red2[0], sigma = red2[1];
        float val = (zv[t] - mu) / (sigma + 1e-3f) * ln_a[t] + ln_b[t];
        sg[b * D + t] = val;
        sgT[t * B_SZ + b] = (_Float16)val;
        qbuf[b * D + t] = emb[query[b] * D + t];
    }
}

// ---------------------------------------------------------------------------
// Kernel 2: gates GEMM via fp16 MFMA + fused LSTM pointwise.
// Workgroup: 64 b-rows x (16 units x 4 gates). 4 waves, wave = 16 b-rows.
// A (x = [q|h|r], f32 sources) staged once to LDS as fp16; W tiles dbuf'd.
// Grid (16, 16).
// ---------------------------------------------------------------------------
__global__ __launch_bounds__(256) void k_gates_mfma(
    const float* __restrict__ qb, const float* __restrict__ hb,
    const float* __restrict__ rp0, const float* __restrict__ rp1,
    const float* __restrict__ w_ih, const float* __restrict__ w_hh,
    const float* __restrict__ b_ih, const float* __restrict__ b_hh,
    float* __restrict__ cbuf, float* __restrict__ hout, int kend, int first)
{
    __shared__ _Float16 Ah[64 * AW];
    __shared__ _Float16 Bh[2][4][16][40];

    const int t = threadIdx.x;
    const int b0 = blockIdx.x * 64;
    const int n0 = blockIdx.y * 16;
    const int lane = t & 63, wv = t >> 6;
    const int m = lane & 15, quad = lane >> 4;

    // ---- stage A: thread t -> row t>>2, col-phase t&3 (f32 -> fp16)
    {
        const int row = t >> 2;
        const int gr = b0 + row;
        for (int c4 = (t & 3) * 4; c4 < kend; c4 += 16) {
            float4 v;
            if (c4 < 128)      v = *(const float4*)&qb[gr * D + c4];
            else if (c4 < 256) v = *(const float4*)&hb[gr * D + (c4 - 128)];
            else {
                float4 a = *(const float4*)&rp0[gr * D + (c4 - 256)];
                float4 bb = *(const float4*)&rp1[gr * D + (c4 - 256)];
                v = make_float4(a.x + bb.x, a.y + bb.y, a.z + bb.z, a.w + bb.w);
            }
            half4 h;
            h[0] = (_Float16)v.x; h[1] = (_Float16)v.y;
            h[2] = (_Float16)v.z; h[3] = (_Float16)v.w;
            *(half4*)&Ah[row * AW + c4] = h;
        }
    }

    // ---- W tile staging: thread t -> gate t>>6, unit (t>>2)&15, k-chunk (t&3)*8
    const int sg_g = t >> 6, sg_u = (t >> 2) & 15, sg_kq = (t & 3) * 8;
    auto stage_b = [&](int ks, int buf) {
        const int grow = sg_g * 256 + n0 + sg_u;
        const int k0 = ks * 32 + sg_kq;
        const float* src = (k0 < 128) ? &w_ih[grow * D + k0]
                                      : &w_hh[grow * TWO_D + (k0 - 128)];
        *(half8*)&Bh[buf][sg_g][sg_u][sg_kq] = cvt8(src);
    };

    stage_b(0, 0);
    __syncthreads();

    floatx4 acc[4];
    #pragma unroll
    for (int g = 0; g < 4; ++g)
        #pragma unroll
        for (int i = 0; i < 4; ++i) acc[g][i] = 0.f;

    const int nsteps = kend >> 5;
    for (int ks = 0; ks < nsteps; ++ks) {
        if (ks + 1 < nsteps) stage_b(ks + 1, (ks + 1) & 1);
        half8 a = *(const half8*)&Ah[(wv * 16 + m) * AW + ks * 32 + quad * 8];
        #pragma unroll
        for (int g = 0; g < 4; ++g) {
            half8 bf = *(const half8*)&Bh[ks & 1][g][m][quad * 8];
            acc[g] = __builtin_amdgcn_mfma_f32_16x16x32_f16(a, bf, acc[g], 0, 0, 0);
        }
        __syncthreads();
    }

    // ---- fused LSTM pointwise epilogue
    const int unit = n0 + m;
    float bi[4];
    #pragma unroll
    for (int g = 0; g < 4; ++g) bi[g] = b_ih[g * 256 + unit] + b_hh[g * 256 + unit];
    #pragma unroll
    for (int rr = 0; rr < 4; ++rr) {
        const int b = b0 + wv * 16 + quad * 4 + rr;
        float gi = acc[0][rr] + bi[0];
        float gf = acc[1][rr] + bi[1];
        float gg = acc[2][rr] + bi[2];
        float go = acc[3][rr] + bi[3];
        float cold = first ? 0.f : cbuf[b * TWO_D + unit];
        float cnew = sigmoid_f(gf) * cold + sigmoid_f(gi) * tanh_fast(gg);
        cbuf[b * TWO_D + unit] = cnew;
        if (n0 < D) {
            float h = sigmoid_f(go) * tanh_fast(cnew);
            hout[b * D + unit] = qb[b * D + unit] + h;
        }
    }
}

// ---------------------------------------------------------------------------
// Kernel 3: scores = h @ sg^T via fp16 MFMA. Workgroup 64x64, wave = 16 rows
// x 64 cols (4 n-tiles). Direct global frag loads (L1/L2 resident), K=128.
// Grid (16, 16).
// ---------------------------------------------------------------------------
__global__ __launch_bounds__(256) void k_scores_mfma(
    const float* __restrict__ h, const float* __restrict__ sg,
    float* __restrict__ scores)
{
    const int t = threadIdx.x;
    const int lane = t & 63, wv = t >> 6;
    const int m = lane & 15, quad = lane >> 4;
    const int b0 = blockIdx.x * 64, j0 = blockIdx.y * 64;
    const int arow = b0 + wv * 16 + m;

    floatx4 acc[4];
    #pragma unroll
    for (int nt = 0; nt < 4; ++nt)
        #pragma unroll
        for (int i = 0; i < 4; ++i) acc[nt][i] = 0.f;

    #pragma unroll
    for (int ks = 0; ks < 4; ++ks) {
        const int k0 = ks * 32 + quad * 8;
        half8 a = cvt8(&h[arow * D + k0]);
        #pragma unroll
        for (int nt = 0; nt < 4; ++nt) {
            half8 bf = cvt8(&sg[(j0 + nt * 16 + m) * D + k0]);
            acc[nt] = __builtin_amdgcn_mfma_f32_16x16x32_f16(a, bf, acc[nt], 0, 0, 0);
        }
    }
    #pragma unroll
    for (int nt = 0; nt < 4; ++nt)
        #pragma unroll
        for (int rr = 0; rr < 4; ++rr)
            scores[(b0 + wv * 16 + quad * 4 + rr) * B_SZ + j0 + nt * 16 + m] = acc[nt][rr];
}

// ---------------------------------------------------------------------------
// Kernel 4: per-row softmax stats (max, 1/sumexp). One block per row.
// ---------------------------------------------------------------------------
__global__ __launch_bounds__(256) void k_stats(
    const float* __restrict__ scores, float2* __restrict__ stats)
{
    __shared__ float red[4];
    __shared__ float smx;
    const int b = blockIdx.x, t = threadIdx.x;
    const float* row = scores + b * B_SZ;
    float v0 = row[t], v1 = row[t + 256], v2 = row[t + 512], v3 = row[t + 768];
    float m = fmaxf(fmaxf(v0, v1), fmaxf(v2, v3));
    for (int off = 32; off; off >>= 1) m = fmaxf(m, __shfl_down(m, off));
    if ((t & 63) == 0) red[t >> 6] = m;
    __syncthreads();
    if (t == 0) smx = fmaxf(fmaxf(red[0], red[1]), fmaxf(red[2], red[3]));
    __syncthreads();
    const float mx = smx;
    float s = __expf(v0 - mx) + __expf(v1 - mx) + __expf(v2 - mx) + __expf(v3 - mx);
    for (int off = 32; off; off >>= 1) s += __shfl_down(s, off);
    __syncthreads();
    if ((t & 63) == 0) red[t >> 6] = s;
    __syncthreads();
    if (t == 0) stats[b] = make_float2(mx, 1.f / (red[0] + red[1] + red[2] + red[3]));
}

// ---------------------------------------------------------------------------
// Kernel 5: r = softmax(scores) @ sg via fp16 MFMA, softmax applied on the
// fly into A-frags; B-frags read k-contiguous from sgT (fp16). Split-K x2
// into rpart[2] (summed by the next gates kernel's staging — no atomics).
// Grid (64, 2), 1 wave per block; wave = 16 rows x 128 cols.
// ---------------------------------------------------------------------------
__global__ __launch_bounds__(64) void k_rgemm_mfma(
    const float* __restrict__ scores, const float2* __restrict__ stats,
    const _Float16* __restrict__ sgT, float* __restrict__ rpart)
{
    const int t = threadIdx.x;
    const int m = t & 15, quad = t >> 4;
    const int m0 = blockIdx.x * 16;
    const int kbase = blockIdx.y * 512;
    const float2 st = stats[m0 + m];

    floatx4 acc[8];
    #pragma unroll
    for (int nt = 0; nt < 8; ++nt)
        #pragma unroll
        for (int i = 0; i < 4; ++i) acc[nt][i] = 0.f;

    #pragma unroll 4
    for (int ks = 0; ks < 16; ++ks) {
        const int k0 = kbase + ks * 32 + quad * 8;
        const float* sp = &scores[(m0 + m) * B_SZ + k0];
        float4 v0 = *(const float4*)sp;
        float4 v1 = *(const float4*)(sp + 4);
        half8 a;
        a[0] = (_Float16)(__expf(v0.x - st.x) * st.y);
        a[1] = (_Float16)(__expf(v0.y - st.x) * st.y);
        a[2] = (_Float16)(__expf(v0.z - st.x) * st.y);
        a[3] = (_Float16)(__expf(v0.w - st.x) * st.y);
        a[4] = (_Float16)(__expf(v1.x - st.x) * st.y);
        a[5] = (_Float16)(__expf(v1.y - st.x) * st.y);
        a[6] = (_Float16)(__expf(v1.z - st.x) * st.y);
        a[7] = (_Float16)(__expf(v1.w - st.x) * st.y);
        #pragma unroll
        for (int nt = 0; nt < 8; ++nt) {
            half8 bf = *(const half8*)&sgT[(nt * 16 + m) * B_SZ + k0];
            acc[nt] = __builtin_amdgcn_mfma_f32_16x16x32_f16(a, bf, acc[nt], 0, 0, 0);
        }
    }
    float* rp = rpart + blockIdx.y * (B_SZ * D);
    #pragma unroll
    for (int nt = 0; nt < 8; ++nt)
        #pragma unroll
        for (int rr = 0; rr < 4; ++rr)
            rp[(m0 + quad * 4 + rr) * D + nt * 16 + m] = acc[nt][rr];
}

// ---------------------------------------------------------------------------
// Kernel 6: cosine similarity per row. One wave per row.
// ---------------------------------------------------------------------------
__global__ __launch_bounds__(64) void k_cosine(
    const float* __restrict__ hout, const float* __restrict__ sg,
    float* __restrict__ out)
{
    const int b = blockIdx.x, t = threadIdx.x;
    float a0 = hout[b * D + t], a1 = hout[b * D + t + 64];
    float s0 = sg[b * D + t], s1 = sg[b * D + t + 64];
    float cr = a0 * s0 + a1 * s1;
    float n1 = a0 * a0 + a1 * a1;
    float n2 = s0 * s0 + s1 * s1;
    for (int off = 32; off; off >>= 1) {
        cr += __shfl_down(cr, off);
        n1 += __shfl_down(n1, off);
        n2 += __shfl_down(n2, off);
    }
    if (t == 0) out[b] = cr / sqrtf(n1 * n2);
}

// ---------------------------------------------------------------------------
extern "C" void kernel_launch(void* const* d_in, const int* in_sizes, int n_in,
                              void* d_out, int out_size, void* d_ws, size_t ws_size,
                              hipStream_t stream)
{
    const int*   relations = (const int*)d_in[0];
    const int*   entities  = (const int*)d_in[1];
    const int*   query     = (const int*)d_in[2];
    const float* emb       = (const float*)d_in[3];
    const float* gcn_w     = (const float*)d_in[4];
    const float* gcn_b     = (const float*)d_in[5];
    const float* p1_w      = (const float*)d_in[6];
    const float* p1_b      = (const float*)d_in[7];
    const float* p2_w      = (const float*)d_in[8];
    const float* p2_b      = (const float*)d_in[9];
    const float* ln_a      = (const float*)d_in[10];
    const float* ln_b      = (const float*)d_in[11];
    const float* w_ih      = (const float*)d_in[12];
    const float* w_hh      = (const float*)d_in[13];
    const float* b_ih      = (const float*)d_in[14];
    const float* b_hh      = (const float*)d_in[15];

    float* ws = (float*)d_ws;
    float*     sg     = ws;                      // 1024*128
    float*     qb     = ws + 131072;             // 1024*128
    float*     hoA    = ws + 262144;             // 1024*128
    float*     hoB    = ws + 393216;             // 1024*128
    float*     rpart  = ws + 524288;             // 2 x 1024*128
    float*     cb     = ws + 786432;             // 1024*256
    float*     scores = ws + 1048576;            // 1024*1024
    float2*    stats  = (float2*)(ws + 2097152); // 1024 float2
    _Float16*  sgT    = (_Float16*)(ws + 2099200); // 128*1024 fp16

    k_support<<<dim3(B_SZ), dim3(256), 0, stream>>>(
        relations, entities, query, emb, gcn_w, gcn_b,
        p1_w, p1_b, p2_w, p2_b, ln_a, ln_b, sg, sgT, qb);

    // step 0 (h_r == 0: kend=128, first=1 -> c starts at 0, no memset needed)
    k_gates_mfma<<<dim3(16, 16), dim3(256), 0, stream>>>(
        qb, hoA, rpart, rpart + 131072, w_ih, w_hh, b_ih, b_hh, cb, hoB, 128, 1);
    k_scores_mfma<<<dim3(16, 16), dim3(256), 0, stream>>>(hoB, sg, scores);
    k_stats<<<dim3(B_SZ), dim3(256), 0, stream>>>(scores, stats);
    k_rgemm_mfma<<<dim3(64, 2), dim3(64), 0, stream>>>(scores, stats, sgT, rpart);

    // step 1
    k_gates_mfma<<<dim3(16, 16), dim3(256), 0, stream>>>(
        qb, hoB, rpart, rpart + 131072, w_ih, w_hh, b_ih, b_hh, cb, hoA, 384, 0);
    k_scores_mfma<<<dim3(16, 16), dim3(256), 0, stream>>>(hoA, sg, scores);
    k_stats<<<dim3(B_SZ), dim3(256), 0, stream>>>(scores, stats);
    k_rgemm_mfma<<<dim3(64, 2), dim3(64), 0, stream>>>(scores, stats, sgT, rpart);

    // step 2
    k_gates_mfma<<<dim3(16, 16), dim3(256), 0, stream>>>(
        qb, hoA, rpart, rpart + 131072, w_ih, w_hh, b_ih, b_hh, cb, hoB, 384, 0);
    k_scores_mfma<<<dim3(16, 16), dim3(256), 0, stream>>>(hoB, sg, scores);
    k_stats<<<dim3(B_SZ), dim3(256), 0, stream>>>(scores, stats);
    k_rgemm_mfma<<<dim3(64, 2), dim3(64), 0, stream>>>(scores, stats, sgT, rpart);

    // step 3 (attention output is dead; gates only)
    k_gates_mfma<<<dim3(16, 16), dim3(256), 0, stream>>>(
        qb, hoB, rpart, rpart + 131072, w_ih, w_hh, b_ih, b_hh, cb, hoA, 384, 0);

    k_cosine<<<dim3(B_SZ), dim3(64), 0, stream>>>(hoA, sg, (float*)d_out);
}

// Round 3
// 338.110 us; speedup vs baseline: 1.6246x; 1.2059x over previous
//
#include <hip/hip_runtime.h>
#include <math.h>

#define D 128
#define TWO_D 256
#define B_SZ 1024
#define KNB 200
#define AW 392  // padded LDS stride (fp16) for gates A tile

typedef _Float16 half8 __attribute__((ext_vector_type(8)));
typedef _Float16 half4 __attribute__((ext_vector_type(4)));
typedef float floatx4 __attribute__((ext_vector_type(4)));

__device__ __forceinline__ float sigmoid_f(float x) { return 1.f / (1.f + __expf(-x)); }
__device__ __forceinline__ float tanh_fast(float x) { return 1.f - 2.f / (__expf(2.f * x) + 1.f); }

// ---------------------------------------------------------------------------
// Kernel 1: gather+sum (float4, 8 split-k groups), GCN linear, support
// encoder (FFN+residual+LayerNorm), query gather; writes f32 + fp16 copies.
// One block per batch row b, 256 threads.
// ---------------------------------------------------------------------------
__global__ __launch_bounds__(256) void k_support(
    const int* __restrict__ relations, const int* __restrict__ entities,
    const int* __restrict__ query, const float* __restrict__ emb,
    const float* __restrict__ gcn_w, const float* __restrict__ gcn_b,
    const float* __restrict__ p1_w, const float* __restrict__ p1_b,
    const float* __restrict__ p2_w, const float* __restrict__ p2_b,
    const float* __restrict__ ln_a, const float* __restrict__ ln_b,
    float* __restrict__ sg, _Float16* __restrict__ sgH, _Float16* __restrict__ sgT,
    float* __restrict__ qbuf, _Float16* __restrict__ qbH)
{
    __shared__ int idxs[2 * KNB];
    __shared__ __align__(16) float part[8][132];
    __shared__ __align__(16) float S[TWO_D];
    __shared__ __align__(16) float sup[D];
    __shared__ __align__(16) float hid[TWO_D];
    __shared__ __align__(16) float zv[D];
    __shared__ float red2[2];

    const int b = blockIdx.x;
    const int t = threadIdx.x;

    for (int i = t; i < KNB; i += 256) idxs[i] = relations[b * KNB + i];
    for (int i = t; i < KNB; i += 256) idxs[KNB + i] = entities[b * KNB + i];
    __syncthreads();

    // ---- gather-sum with float4: group g in 0..7; g<4 -> rel, g>=4 -> ent;
    // group handles indices k === (g&3) (mod 4): 50 rows each, 16B/lane loads.
    {
        const int g = t >> 5, c4 = (t & 31) * 4;
        const int* mi = &idxs[(g >> 2) * KNB];
        float4 a4 = make_float4(0.f, 0.f, 0.f, 0.f);
        #pragma unroll 10
        for (int k = (g & 3); k < KNB; k += 4) {
            float4 v = *(const float4*)&emb[(size_t)mi[k] * D + c4];
            a4.x += v.x; a4.y += v.y; a4.z += v.z; a4.w += v.w;
        }
        *(float4*)&part[g][c4] = a4;
    }
    __syncthreads();
    {
        // S[0:128] = rel sum (groups 0..3), S[128:256] = ent sum (groups 4..7)
        const int half = t >> 7, c = t & 127;
        const float* p = &part[half * 4][0];
        S[t] = (p[c] + p[132 + c]) + (p[264 + c] + p[396 + c]);
    }
    __syncthreads();

    if (t < D) {
        const float4* w4 = (const float4*)(gcn_w + t * TWO_D);
        float dot = 0.f;
        #pragma unroll 8
        for (int f = 0; f < TWO_D / 4; ++f) {
            float4 w = w4[f];
            float4 s = *(const float4*)&S[f * 4];
            dot += w.x * s.x + w.y * s.y + w.z * s.z + w.w * s.w;
        }
        float v = (dot + 200.f * gcn_b[t]) * (1.f / 1024.f);  // num_neighbors = B = 1024
        sup[t] = tanhf(v);
    }
    __syncthreads();

    {
        const float4* w4 = (const float4*)(p1_w + t * D);
        float dot = 0.f;
        #pragma unroll 8
        for (int f = 0; f < D / 4; ++f) {
            float4 w = w4[f];
            float4 s = *(const float4*)&sup[f * 4];
            dot += w.x * s.x + w.y * s.y + w.z * s.z + w.w * s.w;
        }
        float h = dot + p1_b[t];
        hid[t] = h > 0.f ? h : 0.f;
    }
    __syncthreads();

    if (t < D) {
        const float4* w4 = (const float4*)(p2_w + t * TWO_D);
        float dot = 0.f;
        #pragma unroll 8
        for (int f = 0; f < TWO_D / 4; ++f) {
            float4 w = w4[f];
            float4 s = *(const float4*)&hid[f * 4];
            dot += w.x * s.x + w.y * s.y + w.z * s.z + w.w * s.w;
        }
        zv[t] = dot + p2_b[t] + sup[t];
    }
    __syncthreads();

    if (t < 64) {
        float x0 = zv[t], x1 = zv[t + 64];
        float s = x0 + x1;
        for (int off = 32; off; off >>= 1) s += __shfl_down(s, off);
        float mu = __shfl(s, 0) * (1.f / 128.f);
        float d0 = x0 - mu, d1 = x1 - mu;
        float v = d0 * d0 + d1 * d1;
        for (int off = 32; off; off >>= 1) v += __shfl_down(v, off);
        v = __shfl(v, 0);
        if (t == 0) { red2[0] = mu; red2[1] = sqrtf(v * (1.f / 127.f)); }
    }
    __syncthreads();
    if (t < D) {
        float mu = red2[0], sigma = red2[1];
        float val = (zv[t] - mu) / (sigma + 1e-3f) * ln_a[t] + ln_b[t];
        sg[b * D + t] = val;
        sgH[b * D + t] = (_Float16)val;
        sgT[t * B_SZ + b] = (_Float16)val;
        float qv = emb[(size_t)query[b] * D + t];
        qbuf[b * D + t] = qv;
        qbH[b * D + t] = (_Float16)qv;
    }
}

// ---------------------------------------------------------------------------
// Kernel 2: gates GEMM via fp16 MFMA + fused LSTM pointwise.
// A = [qbH | hH | rbH] staged once to LDS (fp16 direct copies); W dbuf'd.
// Grid (16, 16), 256 threads (4 waves x 16 rows).
// ---------------------------------------------------------------------------
__global__ __launch_bounds__(256) void k_gates_mfma(
    const _Float16* __restrict__ qbH, const _Float16* __restrict__ hH,
    const _Float16* __restrict__ rbH,
    const float* __restrict__ w_ih, const float* __restrict__ w_hh,
    const float* __restrict__ b_ih, const float* __restrict__ b_hh,
    const float* __restrict__ qb,
    float* __restrict__ cbuf, float* __restrict__ hout,
    _Float16* __restrict__ houtH, int kend, int first)
{
    __shared__ _Float16 Ah[64 * AW];
    __shared__ _Float16 Bh[2][4][16][40];

    const int t = threadIdx.x;
    const int b0 = blockIdx.x * 64;
    const int n0 = blockIdx.y * 16;
    const int lane = t & 63, wv = t >> 6;
    const int m = lane & 15, quad = lane >> 4;

    // ---- stage A (fp16 sources, 8B copies)
    {
        const int row = t >> 2;
        const int gr = b0 + row;
        for (int c4 = (t & 3) * 4; c4 < kend; c4 += 16) {
            const _Float16* src;
            if (c4 < 128)      src = &qbH[gr * D + c4];
            else if (c4 < 256) src = &hH[gr * D + (c4 - 128)];
            else               src = &rbH[gr * D + (c4 - 256)];
            *(half4*)&Ah[row * AW + c4] = *(const half4*)src;
        }
    }

    const int sg_g = t >> 6, sg_u = (t >> 2) & 15, sg_kq = (t & 3) * 8;
    auto stage_b = [&](int ks, int buf) {
        const int grow = sg_g * 256 + n0 + sg_u;
        const int k0 = ks * 32 + sg_kq;
        const float* src = (k0 < 128) ? &w_ih[grow * D + k0]
                                      : &w_hh[grow * TWO_D + (k0 - 128)];
        float4 v0 = *(const float4*)src;
        float4 v1 = *(const float4*)(src + 4);
        half8 h;
        h[0] = (_Float16)v0.x; h[1] = (_Float16)v0.y; h[2] = (_Float16)v0.z; h[3] = (_Float16)v0.w;
        h[4] = (_Float16)v1.x; h[5] = (_Float16)v1.y; h[6] = (_Float16)v1.z; h[7] = (_Float16)v1.w;
        *(half8*)&Bh[buf][sg_g][sg_u][sg_kq] = h;
    };

    stage_b(0, 0);
    __syncthreads();

    floatx4 acc[4];
    #pragma unroll
    for (int g = 0; g < 4; ++g)
        #pragma unroll
        for (int i = 0; i < 4; ++i) acc[g][i] = 0.f;

    const int nsteps = kend >> 5;
    for (int ks = 0; ks < nsteps; ++ks) {
        if (ks + 1 < nsteps) stage_b(ks + 1, (ks + 1) & 1);
        half8 a = *(const half8*)&Ah[(wv * 16 + m) * AW + ks * 32 + quad * 8];
        #pragma unroll
        for (int g = 0; g < 4; ++g) {
            half8 bf = *(const half8*)&Bh[ks & 1][g][m][quad * 8];
            acc[g] = __builtin_amdgcn_mfma_f32_16x16x32_f16(a, bf, acc[g], 0, 0, 0);
        }
        __syncthreads();
    }

    const int unit = n0 + m;
    float bi[4];
    #pragma unroll
    for (int g = 0; g < 4; ++g) bi[g] = b_ih[g * 256 + unit] + b_hh[g * 256 + unit];
    #pragma unroll
    for (int rr = 0; rr < 4; ++rr) {
        const int b = b0 + wv * 16 + quad * 4 + rr;
        float gi = acc[0][rr] + bi[0];
        float gf = acc[1][rr] + bi[1];
        float gg = acc[2][rr] + bi[2];
        float go = acc[3][rr] + bi[3];
        float cold = first ? 0.f : cbuf[b * TWO_D + unit];
        float cnew = sigmoid_f(gf) * cold + sigmoid_f(gi) * tanh_fast(gg);
        cbuf[b * TWO_D + unit] = cnew;
        if (n0 < D) {
            float h = sigmoid_f(go) * tanh_fast(cnew);
            float ho = qb[b * D + unit] + h;
            hout[b * D + unit] = ho;
            houtH[b * D + unit] = (_Float16)ho;
        }
    }
}

// ---------------------------------------------------------------------------
// Kernel 3: scores = h @ sg^T via fp16 MFMA, pure fp16 frag loads.
// Grid (16, 16), 256 threads; wave = 16 rows x 64 cols.
// ---------------------------------------------------------------------------
__global__ __launch_bounds__(256) void k_scores_mfma(
    const _Float16* __restrict__ hH, const _Float16* __restrict__ sgH,
    float* __restrict__ scores)
{
    const int t = threadIdx.x;
    const int lane = t & 63, wv = t >> 6;
    const int m = lane & 15, quad = lane >> 4;
    const int b0 = blockIdx.x * 64, j0 = blockIdx.y * 64;
    const int arow = b0 + wv * 16 + m;

    floatx4 acc[4];
    #pragma unroll
    for (int nt = 0; nt < 4; ++nt)
        #pragma unroll
        for (int i = 0; i < 4; ++i) acc[nt][i] = 0.f;

    #pragma unroll
    for (int ks = 0; ks < 4; ++ks) {
        const int k0 = ks * 32 + quad * 8;
        half8 a = *(const half8*)&hH[arow * D + k0];
        #pragma unroll
        for (int nt = 0; nt < 4; ++nt) {
            half8 bf = *(const half8*)&sgH[(j0 + nt * 16 + m) * D + k0];
            acc[nt] = __builtin_amdgcn_mfma_f32_16x16x32_f16(a, bf, acc[nt], 0, 0, 0);
        }
    }
    #pragma unroll
    for (int nt = 0; nt < 4; ++nt)
        #pragma unroll
        for (int rr = 0; rr < 4; ++rr)
            scores[(b0 + wv * 16 + quad * 4 + rr) * B_SZ + j0 + nt * 16 + m] = acc[nt][rr];
}

// ---------------------------------------------------------------------------
// Kernel 4: per-row softmax stats (max, 1/sumexp). One block per row.
// ---------------------------------------------------------------------------
__global__ __launch_bounds__(256) void k_stats(
    const float* __restrict__ scores, float2* __restrict__ stats)
{
    __shared__ float red[4];
    __shared__ float smx;
    const int b = blockIdx.x, t = threadIdx.x;
    const float* row = scores + b * B_SZ;
    float v0 = row[t], v1 = row[t + 256], v2 = row[t + 512], v3 = row[t + 768];
    float m = fmaxf(fmaxf(v0, v1), fmaxf(v2, v3));
    for (int off = 32; off; off >>= 1) m = fmaxf(m, __shfl_down(m, off));
    if ((t & 63) == 0) red[t >> 6] = m;
    __syncthreads();
    if (t == 0) smx = fmaxf(fmaxf(red[0], red[1]), fmaxf(red[2], red[3]));
    __syncthreads();
    const float mx = smx;
    float s = __expf(v0 - mx) + __expf(v1 - mx) + __expf(v2 - mx) + __expf(v3 - mx);
    for (int off = 32; off; off >>= 1) s += __shfl_down(s, off);
    __syncthreads();
    if ((t & 63) == 0) red[t >> 6] = s;
    __syncthreads();
    if (t == 0) stats[b] = make_float2(mx, 1.f / (red[0] + red[1] + red[2] + red[3]));
}

// ---------------------------------------------------------------------------
// Kernel 5: r-partials = softmax(scores) @ sg via fp16 MFMA, split-K x8.
// Grid (64 m-tiles, 8 k-chunks), 256 threads (4 waves x 2 n-tiles).
// ---------------------------------------------------------------------------
__global__ __launch_bounds__(256) void k_rgemm_mfma(
    const float* __restrict__ scores, const float2* __restrict__ stats,
    const _Float16* __restrict__ sgT, float* __restrict__ rpart)
{
    const int t = threadIdx.x;
    const int wv = t >> 6, lane = t & 63;
    const int m = lane & 15, quad = lane >> 4;
    const int m0 = blockIdx.x * 16;
    const int kbase = blockIdx.y * 128;
    const float2 st = stats[m0 + m];

    floatx4 acc[2];
    #pragma unroll
    for (int nt = 0; nt < 2; ++nt)
        #pragma unroll
        for (int i = 0; i < 4; ++i) acc[nt][i] = 0.f;

    #pragma unroll
    for (int ks = 0; ks < 4; ++ks) {
        const int k0 = kbase + ks * 32 + quad * 8;
        const float* sp = &scores[(m0 + m) * B_SZ + k0];
        float4 v0 = *(const float4*)sp;
        float4 v1 = *(const float4*)(sp + 4);
        half8 a;
        a[0] = (_Float16)(__expf(v0.x - st.x) * st.y);
        a[1] = (_Float16)(__expf(v0.y - st.x) * st.y);
        a[2] = (_Float16)(__expf(v0.z - st.x) * st.y);
        a[3] = (_Float16)(__expf(v0.w - st.x) * st.y);
        a[4] = (_Float16)(__expf(v1.x - st.x) * st.y);
        a[5] = (_Float16)(__expf(v1.y - st.x) * st.y);
        a[6] = (_Float16)(__expf(v1.z - st.x) * st.y);
        a[7] = (_Float16)(__expf(v1.w - st.x) * st.y);
        #pragma unroll
        for (int nt = 0; nt < 2; ++nt) {
            const int col0 = (wv * 2 + nt) * 16;
            half8 bf = *(const half8*)&sgT[(col0 + m) * B_SZ + k0];
            acc[nt] = __builtin_amdgcn_mfma_f32_16x16x32_f16(a, bf, acc[nt], 0, 0, 0);
        }
    }
    float* rp = rpart + blockIdx.y * (B_SZ * D);
    #pragma unroll
    for (int nt = 0; nt < 2; ++nt)
        #pragma unroll
        for (int rr = 0; rr < 4; ++rr)
            rp[(m0 + quad * 4 + rr) * D + (wv * 2 + nt) * 16 + m] = acc[nt][rr];
}

// ---------------------------------------------------------------------------
// Kernel 5b: rbH = fp16(sum of 8 r-partials). Grid 128 x 256.
// ---------------------------------------------------------------------------
__global__ __launch_bounds__(256) void k_rreduce(
    const float* __restrict__ rpart, _Float16* __restrict__ rbH)
{
    const int i = (blockIdx.x * 256 + threadIdx.x) * 4;
    float4 s = *(const float4*)&rpart[i];
    #pragma unroll
    for (int j = 1; j < 8; ++j) {
        float4 v = *(const float4*)&rpart[j * (B_SZ * D) + i];
        s.x += v.x; s.y += v.y; s.z += v.z; s.w += v.w;
    }
    half4 h;
    h[0] = (_Float16)s.x; h[1] = (_Float16)s.y;
    h[2] = (_Float16)s.z; h[3] = (_Float16)s.w;
    *(half4*)&rbH[i] = h;
}

// ---------------------------------------------------------------------------
// Kernel 6: cosine similarity per row. One wave per row.
// ---------------------------------------------------------------------------
__global__ __launch_bounds__(64) void k_cosine(
    const float* __restrict__ hout, const float* __restrict__ sg,
    float* __restrict__ out)
{
    const int b = blockIdx.x, t = threadIdx.x;
    float a0 = hout[b * D + t], a1 = hout[b * D + t + 64];
    float s0 = sg[b * D + t], s1 = sg[b * D + t + 64];
    float cr = a0 * s0 + a1 * s1;
    float n1 = a0 * a0 + a1 * a1;
    float n2 = s0 * s0 + s1 * s1;
    for (int off = 32; off; off >>= 1) {
        cr += __shfl_down(cr, off);
        n1 += __shfl_down(n1, off);
        n2 += __shfl_down(n2, off);
    }
    if (t == 0) out[b] = cr / sqrtf(n1 * n2);
}

// ---------------------------------------------------------------------------
extern "C" void kernel_launch(void* const* d_in, const int* in_sizes, int n_in,
                              void* d_out, int out_size, void* d_ws, size_t ws_size,
                              hipStream_t stream)
{
    const int*   relations = (const int*)d_in[0];
    const int*   entities  = (const int*)d_in[1];
    const int*   query     = (const int*)d_in[2];
    const float* emb       = (const float*)d_in[3];
    const float* gcn_w     = (const float*)d_in[4];
    const float* gcn_b     = (const float*)d_in[5];
    const float* p1_w      = (const float*)d_in[6];
    const float* p1_b      = (const float*)d_in[7];
    const float* p2_w      = (const float*)d_in[8];
    const float* p2_b      = (const float*)d_in[9];
    const float* ln_a      = (const float*)d_in[10];
    const float* ln_b      = (const float*)d_in[11];
    const float* w_ih      = (const float*)d_in[12];
    const float* w_hh      = (const float*)d_in[13];
    const float* b_ih      = (const float*)d_in[14];
    const float* b_hh      = (const float*)d_in[15];

    float* ws = (float*)d_ws;
    float*     sg     = ws;                        // 131072
    float*     qb     = ws + 131072;               // 131072
    float*     hoA    = ws + 262144;               // 131072
    float*     hoB    = ws + 393216;               // 131072
    float*     cb     = ws + 524288;               // 262144
    float*     scores = ws + 786432;               // 1048576
    float*     rpart  = ws + 1835008;              // 8 x 131072 = 1048576
    float2*    stats  = (float2*)(ws + 2883584);   // 1024 float2 (2048 floats)
    _Float16*  sgH    = (_Float16*)(ws + 2885632); // 65536 float-slots
    _Float16*  sgT    = (_Float16*)(ws + 2951168); // 65536
    _Float16*  qbH    = (_Float16*)(ws + 3016704); // 65536
    _Float16*  hHA    = (_Float16*)(ws + 3082240); // 65536
    _Float16*  hHB    = (_Float16*)(ws + 3147776); // 65536
    _Float16*  rbH    = (_Float16*)(ws + 3213312); // 65536

    k_support<<<dim3(B_SZ), dim3(256), 0, stream>>>(
        relations, entities, query, emb, gcn_w, gcn_b,
        p1_w, p1_b, p2_w, p2_b, ln_a, ln_b, sg, sgH, sgT, qb, qbH);

    // step 0 (h_r == 0: kend=128, first=1)
    k_gates_mfma<<<dim3(16, 16), dim3(256), 0, stream>>>(
        qbH, hHA, rbH, w_ih, w_hh, b_ih, b_hh, qb, cb, hoB, hHB, 128, 1);
    k_scores_mfma<<<dim3(16, 16), dim3(256), 0, stream>>>(hHB, sgH, scores);
    k_stats<<<dim3(B_SZ), dim3(256), 0, stream>>>(scores, stats);
    k_rgemm_mfma<<<dim3(64, 8), dim3(256), 0, stream>>>(scores, stats, sgT, rpart);
    k_rreduce<<<dim3(128), dim3(256), 0, stream>>>(rpart, rbH);

    // step 1
    k_gates_mfma<<<dim3(16, 16), dim3(256), 0, stream>>>(
        qbH, hHB, rbH, w_ih, w_hh, b_ih, b_hh, qb, cb, hoA, hHA, 384, 0);
    k_scores_mfma<<<dim3(16, 16), dim3(256), 0, stream>>>(hHA, sgH, scores);
    k_stats<<<dim3(B_SZ), dim3(256), 0, stream>>>(scores, stats);
    k_rgemm_mfma<<<dim3(64, 8), dim3(256), 0, stream>>>(scores, stats, sgT, rpart);
    k_rreduce<<<dim3(128), dim3(256), 0, stream>>>(rpart, rbH);

    // step 2
    k_gates_mfma<<<dim3(16, 16), dim3(256), 0, stream>>>(
        qbH, hHA, rbH, w_ih, w_hh, b_ih, b_hh, qb, cb, hoB, hHB, 384, 0);
    k_scores_mfma<<<dim3(16, 16), dim3(256), 0, stream>>>(hHB, sgH, scores);
    k_stats<<<dim3(B_SZ), dim3(256), 0, stream>>>(scores, stats);
    k_rgemm_mfma<<<dim3(64, 8), dim3(256), 0, stream>>>(scores, stats, sgT, rpart);
    k_rreduce<<<dim3(128), dim3(256), 0, stream>>>(rpart, rbH);

    // step 3 (attention output is dead; gates only)
    k_gates_mfma<<<dim3(16, 16), dim3(256), 0, stream>>>(
        qbH, hHB, rbH, w_ih, w_hh, b_ih, b_hh, qb, cb, hoA, hHA, 384, 0);

    k_cosine<<<dim3(B_SZ), dim3(64), 0, stream>>>(hoA, sg, (float*)d_out);
}

// Round 5
// 319.182 us; speedup vs baseline: 1.7210x; 1.0593x over previous
//
#include <hip/hip_runtime.h>
#include <math.h>

#define D 128
#define TWO_D 256
#define B_SZ 1024
#define KNB 200
#define AW 392  // padded LDS stride (fp16) for gates A tile
#define NKC 4   // split-K chunks in r-GEMM

typedef _Float16 half8 __attribute__((ext_vector_type(8)));
typedef _Float16 half4 __attribute__((ext_vector_type(4)));
typedef float floatx4 __attribute__((ext_vector_type(4)));

__device__ __forceinline__ float sigmoid_f(float x) { return 1.f / (1.f + __expf(-x)); }
__device__ __forceinline__ float tanh_fast(float x) { return 1.f - 2.f / (__expf(2.f * x) + 1.f); }

// ---------------------------------------------------------------------------
// Kernel 0: one-time fp16 conversion of LSTM weights.
// w16 = [w_ih (1024x128) | w_hh (1024x256)] as fp16. 192 blocks x 256 thr.
// ---------------------------------------------------------------------------
__global__ __launch_bounds__(256) void k_cvtw(
    const float* __restrict__ w_ih, const float* __restrict__ w_hh,
    _Float16* __restrict__ w16)
{
    const int i8 = (blockIdx.x * 256 + threadIdx.x) * 8;
    const float* src = (i8 < 131072) ? (w_ih + i8) : (w_hh + (i8 - 131072));
    float4 v0 = *(const float4*)src;
    float4 v1 = *(const float4*)(src + 4);
    half8 h;
    h[0] = (_Float16)v0.x; h[1] = (_Float16)v0.y; h[2] = (_Float16)v0.z; h[3] = (_Float16)v0.w;
    h[4] = (_Float16)v1.x; h[5] = (_Float16)v1.y; h[6] = (_Float16)v1.z; h[7] = (_Float16)v1.w;
    *(half8*)&w16[i8] = h;
}

// ---------------------------------------------------------------------------
// Kernel 1: gather+sum (float4, 16 split-k groups, 8 waves for MLP), GCN
// linear, support encoder, query gather; writes f32 + fp16 copies.
// One block per batch row b, 512 threads.
// ---------------------------------------------------------------------------
__global__ __launch_bounds__(512) void k_support(
    const int* __restrict__ relations, const int* __restrict__ entities,
    const int* __restrict__ query, const float* __restrict__ emb,
    const float* __restrict__ gcn_w, const float* __restrict__ gcn_b,
    const float* __restrict__ p1_w, const float* __restrict__ p1_b,
    const float* __restrict__ p2_w, const float* __restrict__ p2_b,
    const float* __restrict__ ln_a, const float* __restrict__ ln_b,
    float* __restrict__ sg, _Float16* __restrict__ sgH, _Float16* __restrict__ sgT,
    float* __restrict__ qbuf, _Float16* __restrict__ qbH)
{
    __shared__ int idxs[2 * KNB];
    __shared__ __align__(16) float part[16][132];
    __shared__ __align__(16) float S[TWO_D];
    __shared__ __align__(16) float sup[D];
    __shared__ __align__(16) float hid[TWO_D];
    __shared__ __align__(16) float zv[D];
    __shared__ float red2[2];

    const int b = blockIdx.x;
    const int t = threadIdx.x;

    if (t < KNB) idxs[t] = relations[b * KNB + t];
    else if (t < 2 * KNB) idxs[t] = entities[b * KNB + (t - KNB)];
    __syncthreads();

    // ---- gather-sum: 16 groups of 32 lanes; g<8 -> rel, g>=8 -> ent;
    // group g sums rows k === (g&7) (mod 8): 25 rows, float4 per lane.
    {
        const int g = t >> 5, c4 = (t & 31) * 4;
        const int* mi = &idxs[(g >> 3) * KNB];
        float4 a4 = make_float4(0.f, 0.f, 0.f, 0.f);
        #pragma unroll 5
        for (int k = (g & 7); k < KNB; k += 8) {
            float4 v = *(const float4*)&emb[(size_t)mi[k] * D + c4];
            a4.x += v.x; a4.y += v.y; a4.z += v.z; a4.w += v.w;
        }
        *(float4*)&part[g][c4] = a4;
    }
    __syncthreads();
    if (t < TWO_D) {
        const int half = t >> 7, c = t & 127;
        float s = 0.f;
        #pragma unroll
        for (int j = 0; j < 8; ++j) s += part[half * 8 + j][c];
        S[t] = s;
    }
    __syncthreads();

    if (t < D) {
        const float4* w4 = (const float4*)(gcn_w + t * TWO_D);
        float dot = 0.f;
        #pragma unroll 8
        for (int f = 0; f < TWO_D / 4; ++f) {
            float4 w = w4[f];
            float4 s = *(const float4*)&S[f * 4];
            dot += w.x * s.x + w.y * s.y + w.z * s.z + w.w * s.w;
        }
        float v = (dot + 200.f * gcn_b[t]) * (1.f / 1024.f);  // num_neighbors = B = 1024
        sup[t] = tanhf(v);
    }
    __syncthreads();

    if (t < TWO_D) {
        const float4* w4 = (const float4*)(p1_w + t * D);
        float dot = 0.f;
        #pragma unroll 8
        for (int f = 0; f < D / 4; ++f) {
            float4 w = w4[f];
            float4 s = *(const float4*)&sup[f * 4];
            dot += w.x * s.x + w.y * s.y + w.z * s.z + w.w * s.w;
        }
        float h = dot + p1_b[t];
        hid[t] = h > 0.f ? h : 0.f;
    }
    __syncthreads();

    if (t < D) {
        const float4* w4 = (const float4*)(p2_w + t * TWO_D);
        float dot = 0.f;
        #pragma unroll 8
        for (int f = 0; f < TWO_D / 4; ++f) {
            float4 w = w4[f];
            float4 s = *(const float4*)&hid[f * 4];
            dot += w.x * s.x + w.y * s.y + w.z * s.z + w.w * s.w;
        }
        zv[t] = dot + p2_b[t] + sup[t];
    }
    __syncthreads();

    if (t < 64) {
        float x0 = zv[t], x1 = zv[t + 64];
        float s = x0 + x1;
        for (int off = 32; off; off >>= 1) s += __shfl_down(s, off);
        float mu = __shfl(s, 0) * (1.f / 128.f);
        float d0 = x0 - mu, d1 = x1 - mu;
        float v = d0 * d0 + d1 * d1;
        for (int off = 32; off; off >>= 1) v += __shfl_down(v, off);
        v = __shfl(v, 0);
        if (t == 0) { red2[0] = mu; red2[1] = sqrtf(v * (1.f / 127.f)); }
    }
    __syncthreads();
    if (t < D) {
        float mu = red2[0], sigma = red2[1];
        float val = (zv[t] - mu) / (sigma + 1e-3f) * ln_a[t] + ln_b[t];
        sg[b * D + t] = val;
        sgH[b * D + t] = (_Float16)val;
        sgT[t * B_SZ + b] = (_Float16)val;
        float qv = emb[(size_t)query[b] * D + t];
        qbuf[b * D + t] = qv;
        qbH[b * D + t] = (_Float16)qv;
    }
}

// ---------------------------------------------------------------------------
// Kernel 2: gates GEMM via fp16 MFMA + fused LSTM pointwise.
// A = [qbH | hH | sum of NKC r-partials] staged to LDS; W from fp16 w16.
// Grid (16, 16), 256 threads (4 waves x 16 rows).
// ---------------------------------------------------------------------------
__global__ __launch_bounds__(256) void k_gates_mfma(
    const _Float16* __restrict__ qbH, const _Float16* __restrict__ hH,
    const float* __restrict__ rpart, const _Float16* __restrict__ w16,
    const float* __restrict__ b_ih, const float* __restrict__ b_hh,
    const float* __restrict__ qb,
    float* __restrict__ cbuf, float* __restrict__ hout,
    _Float16* __restrict__ houtH, int kend, int first)
{
    __shared__ _Float16 Ah[64 * AW];
    __shared__ _Float16 Bh[2][4][16][40];

    const int t = threadIdx.x;
    const int b0 = blockIdx.x * 64;
    const int n0 = blockIdx.y * 16;
    const int lane = t & 63, wv = t >> 6;
    const int m = lane & 15, quad = lane >> 4;

    // ---- stage A
    {
        const int row = t >> 2;
        const int gr = b0 + row;
        for (int c4 = (t & 3) * 4; c4 < kend; c4 += 16) {
            half4 h;
            if (c4 < 128) {
                h = *(const half4*)&qbH[gr * D + c4];
            } else if (c4 < 256) {
                h = *(const half4*)&hH[gr * D + (c4 - 128)];
            } else {
                const int c = c4 - 256;
                float4 s4 = *(const float4*)&rpart[gr * D + c];
                #pragma unroll
                for (int j = 1; j < NKC; ++j) {
                    float4 v = *(const float4*)&rpart[j * (B_SZ * D) + gr * D + c];
                    s4.x += v.x; s4.y += v.y; s4.z += v.z; s4.w += v.w;
                }
                h[0] = (_Float16)s4.x; h[1] = (_Float16)s4.y;
                h[2] = (_Float16)s4.z; h[3] = (_Float16)s4.w;
            }
            *(half4*)&Ah[row * AW + c4] = h;
        }
    }

    const int sg_g = t >> 6, sg_u = (t >> 2) & 15, sg_kq = (t & 3) * 8;
    auto stage_b = [&](int ks, int buf) {
        const int grow = sg_g * 256 + n0 + sg_u;
        const int k0 = ks * 32 + sg_kq;
        const _Float16* src = (k0 < 128) ? &w16[grow * D + k0]
                                         : &w16[131072 + grow * TWO_D + (k0 - 128)];
        *(half8*)&Bh[buf][sg_g][sg_u][sg_kq] = *(const half8*)src;
    };

    stage_b(0, 0);
    __syncthreads();

    floatx4 acc[4];
    #pragma unroll
    for (int g = 0; g < 4; ++g)
        #pragma unroll
        for (int i = 0; i < 4; ++i) acc[g][i] = 0.f;

    const int nsteps = kend >> 5;
    for (int ks = 0; ks < nsteps; ++ks) {
        if (ks + 1 < nsteps) stage_b(ks + 1, (ks + 1) & 1);
        half8 a = *(const half8*)&Ah[(wv * 16 + m) * AW + ks * 32 + quad * 8];
        #pragma unroll
        for (int g = 0; g < 4; ++g) {
            half8 bf = *(const half8*)&Bh[ks & 1][g][m][quad * 8];
            acc[g] = __builtin_amdgcn_mfma_f32_16x16x32_f16(a, bf, acc[g], 0, 0, 0);
        }
        __syncthreads();
    }

    const int unit = n0 + m;
    float bi[4];
    #pragma unroll
    for (int g = 0; g < 4; ++g) bi[g] = b_ih[g * 256 + unit] + b_hh[g * 256 + unit];
    #pragma unroll
    for (int rr = 0; rr < 4; ++rr) {
        const int b = b0 + wv * 16 + quad * 4 + rr;
        float gi = acc[0][rr] + bi[0];
        float gf = acc[1][rr] + bi[1];
        float gg = acc[2][rr] + bi[2];
        float go = acc[3][rr] + bi[3];
        float cold = first ? 0.f : cbuf[b * TWO_D + unit];
        float cnew = sigmoid_f(gf) * cold + sigmoid_f(gi) * tanh_fast(gg);
        cbuf[b * TWO_D + unit] = cnew;
        if (n0 < D) {
            float h = sigmoid_f(go) * tanh_fast(cnew);
            float ho = qb[b * D + unit] + h;
            hout[b * D + unit] = ho;
            houtH[b * D + unit] = (_Float16)ho;
        }
    }
}

// ---------------------------------------------------------------------------
// Kernel 3: scores = h @ sg^T via fp16 MFMA, pure fp16 frag loads.
// Grid (16, 16), 256 threads; wave = 16 rows x 64 cols.
// ---------------------------------------------------------------------------
__global__ __launch_bounds__(256) void k_scores_mfma(
    const _Float16* __restrict__ hH, const _Float16* __restrict__ sgH,
    float* __restrict__ scores)
{
    const int t = threadIdx.x;
    const int lane = t & 63, wv = t >> 6;
    const int m = lane & 15, quad = lane >> 4;
    const int b0 = blockIdx.x * 64, j0 = blockIdx.y * 64;
    const int arow = b0 + wv * 16 + m;

    floatx4 acc[4];
    #pragma unroll
    for (int nt = 0; nt < 4; ++nt)
        #pragma unroll
        for (int i = 0; i < 4; ++i) acc[nt][i] = 0.f;

    #pragma unroll
    for (int ks = 0; ks < 4; ++ks) {
        const int k0 = ks * 32 + quad * 8;
        half8 a = *(const half8*)&hH[arow * D + k0];
        #pragma unroll
        for (int nt = 0; nt < 4; ++nt) {
            half8 bf = *(const half8*)&sgH[(j0 + nt * 16 + m) * D + k0];
            acc[nt] = __builtin_amdgcn_mfma_f32_16x16x32_f16(a, bf, acc[nt], 0, 0, 0);
        }
    }
    #pragma unroll
    for (int nt = 0; nt < 4; ++nt)
        #pragma unroll
        for (int rr = 0; rr < 4; ++rr)
            scores[(b0 + wv * 16 + quad * 4 + rr) * B_SZ + j0 + nt * 16 + m] = acc[nt][rr];
}

// ---------------------------------------------------------------------------
// Kernel 4: r-partials = softmax(scores) @ sg via fp16 MFMA, split-K x NKC,
// with per-block softmax stats (register-cached rows, wave reductions).
// Grid (64 m-tiles, NKC k-chunks), 256 threads (4 waves x 2 n-tiles).
// ---------------------------------------------------------------------------
__global__ __launch_bounds__(256) void k_rgemm_mfma(
    const float* __restrict__ scores, const _Float16* __restrict__ sgT,
    float* __restrict__ rpart)
{
    __shared__ float st_lds[16][2];

    const int t = threadIdx.x;
    const int wv = t >> 6, lane = t & 63;
    const int m = lane & 15, quad = lane >> 4;
    const int m0 = blockIdx.x * 16;
    const int kbase = blockIdx.y * (B_SZ / NKC);

    // ---- phase 1: stats for rows m0..m0+15 (wave wv -> rows wv*4..wv*4+3)
    #pragma unroll
    for (int r = 0; r < 4; ++r) {
        const int row = m0 + wv * 4 + r;
        const float* sp = &scores[row * B_SZ + lane * 16];
        float4 c0 = *(const float4*)sp;
        float4 c1 = *(const float4*)(sp + 4);
        float4 c2 = *(const float4*)(sp + 8);
        float4 c3 = *(const float4*)(sp + 12);
        float mm = fmaxf(fmaxf(fmaxf(c0.x, c0.y), fmaxf(c0.z, c0.w)),
                  fmaxf(fmaxf(fmaxf(c1.x, c1.y), fmaxf(c1.z, c1.w)),
                  fmaxf(fmaxf(fmaxf(c2.x, c2.y), fmaxf(c2.z, c2.w)),
                        fmaxf(fmaxf(c3.x, c3.y), fmaxf(c3.z, c3.w)))));
        for (int off = 32; off; off >>= 1) mm = fmaxf(mm, __shfl_down(mm, off));
        mm = __shfl(mm, 0);
        float ss = __expf(c0.x - mm) + __expf(c0.y - mm) + __expf(c0.z - mm) + __expf(c0.w - mm)
                 + __expf(c1.x - mm) + __expf(c1.y - mm) + __expf(c1.z - mm) + __expf(c1.w - mm)
                 + __expf(c2.x - mm) + __expf(c2.y - mm) + __expf(c2.z - mm) + __expf(c2.w - mm)
                 + __expf(c3.x - mm) + __expf(c3.y - mm) + __expf(c3.z - mm) + __expf(c3.w - mm);
        for (int off = 32; off; off >>= 1) ss += __shfl_down(ss, off);
        if (lane == 0) { st_lds[wv * 4 + r][0] = mm; st_lds[wv * 4 + r][1] = 1.f / ss; }
    }
    __syncthreads();
    const float stx = st_lds[m][0], sty = st_lds[m][1];

    // ---- phase 2: split-K MFMA
    floatx4 acc[2];
    #pragma unroll
    for (int nt = 0; nt < 2; ++nt)
        #pragma unroll
        for (int i = 0; i < 4; ++i) acc[nt][i] = 0.f;

    #pragma unroll
    for (int ks = 0; ks < (B_SZ / NKC) / 32; ++ks) {
        const int k0 = kbase + ks * 32 + quad * 8;
        const float* sp = &scores[(m0 + m) * B_SZ + k0];
        float4 v0 = *(const float4*)sp;
        float4 v1 = *(const float4*)(sp + 4);
        half8 a;
        a[0] = (_Float16)(__expf(v0.x - stx) * sty);
        a[1] = (_Float16)(__expf(v0.y - stx) * sty);
        a[2] = (_Float16)(__expf(v0.z - stx) * sty);
        a[3] = (_Float16)(__expf(v0.w - stx) * sty);
        a[4] = (_Float16)(__expf(v1.x - stx) * sty);
        a[5] = (_Float16)(__expf(v1.y - stx) * sty);
        a[6] = (_Float16)(__expf(v1.z - stx) * sty);
        a[7] = (_Float16)(__expf(v1.w - stx) * sty);
        #pragma unroll
        for (int nt = 0; nt < 2; ++nt) {
            const int col0 = (wv * 2 + nt) * 16;
            half8 bf = *(const half8*)&sgT[(col0 + m) * B_SZ + k0];
            acc[nt] = __builtin_amdgcn_mfma_f32_16x16x32_f16(a, bf, acc[nt], 0, 0, 0);
        }
    }
    float* rp = rpart + blockIdx.y * (B_SZ * D);
    #pragma unroll
    for (int nt = 0; nt < 2; ++nt)
        #pragma unroll
        for (int rr = 0; rr < 4; ++rr)
            rp[(m0 + quad * 4 + rr) * D + (wv * 2 + nt) * 16 + m] = acc[nt][rr];
}

// ---------------------------------------------------------------------------
// Kernel 5: cosine similarity per row. One wave per row.
// ---------------------------------------------------------------------------
__global__ __launch_bounds__(64) void k_cosine(
    const float* __restrict__ hout, const float* __restrict__ sg,
    float* __restrict__ out)
{
    const int b = blockIdx.x, t = threadIdx.x;
    float a0 = hout[b * D + t], a1 = hout[b * D + t + 64];
    float s0 = sg[b * D + t], s1 = sg[b * D + t + 64];
    float cr = a0 * s0 + a1 * s1;
    float n1 = a0 * a0 + a1 * a1;
    float n2 = s0 * s0 + s1 * s1;
    for (int off = 32; off; off >>= 1) {
        cr += __shfl_down(cr, off);
        n1 += __shfl_down(n1, off);
        n2 += __shfl_down(n2, off);
    }
    if (t == 0) out[b] = cr / sqrtf(n1 * n2);
}

// ---------------------------------------------------------------------------
extern "C" void kernel_launch(void* const* d_in, const int* in_sizes, int n_in,
                              void* d_out, int out_size, void* d_ws, size_t ws_size,
                              hipStream_t stream)
{
    const int*   relations = (const int*)d_in[0];
    const int*   entities  = (const int*)d_in[1];
    const int*   query     = (const int*)d_in[2];
    const float* emb       = (const float*)d_in[3];
    const float* gcn_w     = (const float*)d_in[4];
    const float* gcn_b     = (const float*)d_in[5];
    const float* p1_w      = (const float*)d_in[6];
    const float* p1_b      = (const float*)d_in[7];
    const float* p2_w      = (const float*)d_in[8];
    const float* p2_b      = (const float*)d_in[9];
    const float* ln_a      = (const float*)d_in[10];
    const float* ln_b      = (const float*)d_in[11];
    const float* w_ih      = (const float*)d_in[12];
    const float* w_hh      = (const float*)d_in[13];
    const float* b_ih      = (const float*)d_in[14];
    const float* b_hh      = (const float*)d_in[15];

    // Workspace layout (float-slot offsets). fp16 buffers of 1024x128 halves
    // occupy 65536 float-slots EACH (262144 bytes) — round-4 bug was 32768.
    float* ws = (float*)d_ws;
    float*     sg     = ws;                        // 131072
    float*     qb     = ws + 131072;               // 131072
    float*     hoA    = ws + 262144;               // 131072
    float*     hoB    = ws + 393216;               // 131072
    float*     cb     = ws + 524288;               // 262144
    float*     scores = ws + 786432;               // 1048576
    float*     rpart  = ws + 1835008;              // NKC x 131072 = 524288
    _Float16*  sgH    = (_Float16*)(ws + 2359296); // 65536 float-slots each
    _Float16*  sgT    = (_Float16*)(ws + 2424832);
    _Float16*  qbH    = (_Float16*)(ws + 2490368);
    _Float16*  hHA    = (_Float16*)(ws + 2555904);
    _Float16*  hHB    = (_Float16*)(ws + 2621440);
    _Float16*  w16    = (_Float16*)(ws + 2686976); // 393216 halves = 196608 slots
    // end: 2883584 floats = 11.53 MB

    k_cvtw<<<dim3(192), dim3(256), 0, stream>>>(w_ih, w_hh, w16);
    k_support<<<dim3(B_SZ), dim3(512), 0, stream>>>(
        relations, entities, query, emb, gcn_w, gcn_b,
        p1_w, p1_b, p2_w, p2_b, ln_a, ln_b, sg, sgH, sgT, qb, qbH);

    // step 0 (h_r == 0: kend=128, first=1 -> h/r segments never read)
    k_gates_mfma<<<dim3(16, 16), dim3(256), 0, stream>>>(
        qbH, hHA, rpart, w16, b_ih, b_hh, qb, cb, hoB, hHB, 128, 1);
    k_scores_mfma<<<dim3(16, 16), dim3(256), 0, stream>>>(hHB, sgH, scores);
    k_rgemm_mfma<<<dim3(64, NKC), dim3(256), 0, stream>>>(scores, sgT, rpart);

    // step 1
    k_gates_mfma<<<dim3(16, 16), dim3(256), 0, stream>>>(
        qbH, hHB, rpart, w16, b_ih, b_hh, qb, cb, hoA, hHA, 384, 0);
    k_scores_mfma<<<dim3(16, 16), dim3(256), 0, stream>>>(hHA, sgH, scores);
    k_rgemm_mfma<<<dim3(64, NKC), dim3(256), 0, stream>>>(scores, sgT, rpart);

    // step 2
    k_gates_mfma<<<dim3(16, 16), dim3(256), 0, stream>>>(
        qbH, hHA, rpart, w16, b_ih, b_hh, qb, cb, hoB, hHB, 384, 0);
    k_scores_mfma<<<dim3(16, 16), dim3(256), 0, stream>>>(hHB, sgH, scores);
    k_rgemm_mfma<<<dim3(64, NKC), dim3(256), 0, stream>>>(scores, sgT, rpart);

    // step 3 (attention output is dead; gates only)
    k_gates_mfma<<<dim3(16, 16), dim3(256), 0, stream>>>(
        qbH, hHB, rpart, w16, b_ih, b_hh, qb, cb, hoA, hHA, 384, 0);

    k_cosine<<<dim3(B_SZ), dim3(64), 0, stream>>>(hoA, sg, (float*)d_out);
}